// Round 9
// baseline (95.550 us; speedup 1.0000x reference)
//
#include <hip/hip_runtime.h>
#include <math.h>

#define NN 2048
#define DD 64
#define HH 64

// ---------------------------------------------------------------------------
// Stage 1: u[i][h] = z[i]·Wa[h] + b1[h]; v[i][h] = z[i]·Wb[h]
// Plus fused rank-1 terms: a[i] = 0.5*sum_h W2[h]*u[i][h], b[i] = same on v.
// (unchanged from round 7 — passing)
// ---------------------------------------------------------------------------
__global__ __launch_bounds__(256) void prep_kernel(
    const float* __restrict__ z, const float* __restrict__ W1,
    const float* __restrict__ b1, const float* __restrict__ W2,
    float* __restrict__ u, float* __restrict__ v,
    float* __restrict__ a, float* __restrict__ b) {
  __shared__ float zs[8 * DD];
  const int t = threadIdx.x;
  const int i0 = blockIdx.x * 8;
  if (t < 128) {
    reinterpret_cast<float4*>(zs)[t] =
        reinterpret_cast<const float4*>(z + (size_t)i0 * DD)[t];
  }
  __syncthreads();

  const int hs = t & 127;
  const int rg = t >> 7;
  const int h = hs & 63;
  const int side = hs >> 6;
  const float* wrow = W1 + h * (2 * DD) + side * DD;

  float acc0 = 0.f, acc1 = 0.f, acc2 = 0.f, acc3 = 0.f;
#pragma unroll
  for (int d4 = 0; d4 < DD / 4; ++d4) {
    const float4 wv = reinterpret_cast<const float4*>(wrow)[d4];
    const float* z0 = zs + (rg * 4 + 0) * DD + d4 * 4;
    const float* z1 = z0 + DD;
    const float* z2 = z1 + DD;
    const float* z3 = z2 + DD;
    acc0 = fmaf(z0[3], wv.w, fmaf(z0[2], wv.z, fmaf(z0[1], wv.y, fmaf(z0[0], wv.x, acc0))));
    acc1 = fmaf(z1[3], wv.w, fmaf(z1[2], wv.z, fmaf(z1[1], wv.y, fmaf(z1[0], wv.x, acc1))));
    acc2 = fmaf(z2[3], wv.w, fmaf(z2[2], wv.z, fmaf(z2[1], wv.y, fmaf(z2[0], wv.x, acc2))));
    acc3 = fmaf(z3[3], wv.w, fmaf(z3[2], wv.z, fmaf(z3[1], wv.y, fmaf(z3[0], wv.x, acc3))));
  }
  const float bias = side ? 0.0f : b1[h];
  const float s0 = acc0 + bias, s1 = acc1 + bias, s2 = acc2 + bias, s3 = acc3 + bias;
  float* dst = side ? v : u;
  const int ib = i0 + rg * 4;
  dst[(size_t)(ib + 0) * HH + h] = s0;
  dst[(size_t)(ib + 1) * HH + h] = s1;
  dst[(size_t)(ib + 2) * HH + h] = s2;
  dst[(size_t)(ib + 3) * HH + h] = s3;

  const float wh = W2[h];
  float r0 = wh * s0, r1 = wh * s1, r2 = wh * s2, r3 = wh * s3;
#pragma unroll
  for (int m = 1; m < 64; m <<= 1) {
    r0 += __shfl_xor(r0, m);
    r1 += __shfl_xor(r1, m);
    r2 += __shfl_xor(r2, m);
    r3 += __shfl_xor(r3, m);
  }
  if ((t & 63) == 0) {
    float* d2 = side ? b : a;
    d2[ib + 0] = 0.5f * r0;
    d2[ib + 1] = 0.5f * r1;
    d2[ib + 2] = 0.5f * r2;
    d2[ib + 3] = 0.5f * r3;
  }
}

// ---------------------------------------------------------------------------
// Stage 2: out[i][j] = sigmoid(a[i]+b[j]+b2 + 0.5*sum_h W2[h]*|u[i,h]+v[j,h]|),
// diagonal zeroed.
// Structure: lane owns 4 j-columns (v in registers from global, L1/L2-hot);
// u comes from LDS via same-address broadcast b128 (conflict-free).
// Per wave: 8 i-rows x 256 j. Per h: 2 LDS broadcasts + 64 VALU ops
// -> LDS pipe ~8k cyc/CU vs VALU 16.4k cyc/CU: VALU-bound with 2x margin.
// Block: 4 waves (i-tile 32), j-tile 256; grid 8x64=512 = 2 blocks/CU.
// ---------------------------------------------------------------------------
__global__ __launch_bounds__(256, 2) void pair_kernel(
    const float* __restrict__ u, const float* __restrict__ v,
    const float* __restrict__ a, const float* __restrict__ b,
    const float* __restrict__ W2, const float* __restrict__ b2,
    float* __restrict__ out) {
  __shared__ float su[HH][36];  // [h][i-local 0..31], pad 36 (9.2 KB)

  const int t = threadIdx.x;
  const int i0 = blockIdx.y * 32;
  const int j0 = blockIdx.x * 256;

  // stage u-tile (32 rows x 64 h) transposed, in-register 4x4 transpose
  if (t < 128) {
    const int r = t >> 4;  // i-quad 0..7
    const int c = t & 15;  // h-quad 0..15
    const float* us = u + (size_t)(i0 + 4 * r) * HH + 4 * c;
    const float4 a0 = *reinterpret_cast<const float4*>(us);
    const float4 a1 = *reinterpret_cast<const float4*>(us + HH);
    const float4 a2 = *reinterpret_cast<const float4*>(us + 2 * HH);
    const float4 a3 = *reinterpret_cast<const float4*>(us + 3 * HH);
    *reinterpret_cast<float4*>(&su[4 * c + 0][4 * r]) = make_float4(a0.x, a1.x, a2.x, a3.x);
    *reinterpret_cast<float4*>(&su[4 * c + 1][4 * r]) = make_float4(a0.y, a1.y, a2.y, a3.y);
    *reinterpret_cast<float4*>(&su[4 * c + 2][4 * r]) = make_float4(a0.z, a1.z, a2.z, a3.z);
    *reinterpret_cast<float4*>(&su[4 * c + 3][4 * r]) = make_float4(a0.w, a1.w, a2.w, a3.w);
  }
  __syncthreads();

  const int L = t & 63;   // lane
  const int w = t >> 6;   // wave 0..3
  const int ib = w * 8;   // wave's i-offset within tile

  const float* vr0 = v + (size_t)(j0 + L) * HH;
  const float* vr1 = v + (size_t)(j0 + 64 + L) * HH;
  const float* vr2 = v + (size_t)(j0 + 128 + L) * HH;
  const float* vr3 = v + (size_t)(j0 + 192 + L) * HH;

  float acc[8][4] = {};
  for (int hc = 0; hc < 8; ++hc) {  // 8 chunks of 8 h
    const float4 wq0 = *reinterpret_cast<const float4*>(W2 + hc * 8);      // uniform -> s_load
    const float4 wq1 = *reinterpret_cast<const float4*>(W2 + hc * 8 + 4);
    const float wa[8] = {wq0.x, wq0.y, wq0.z, wq0.w, wq1.x, wq1.y, wq1.z, wq1.w};
    const float4 v00 = *reinterpret_cast<const float4*>(vr0 + hc * 8);
    const float4 v01 = *reinterpret_cast<const float4*>(vr0 + hc * 8 + 4);
    const float4 v10 = *reinterpret_cast<const float4*>(vr1 + hc * 8);
    const float4 v11 = *reinterpret_cast<const float4*>(vr1 + hc * 8 + 4);
    const float4 v20 = *reinterpret_cast<const float4*>(vr2 + hc * 8);
    const float4 v21 = *reinterpret_cast<const float4*>(vr2 + hc * 8 + 4);
    const float4 v30 = *reinterpret_cast<const float4*>(vr3 + hc * 8);
    const float4 v31 = *reinterpret_cast<const float4*>(vr3 + hc * 8 + 4);
    const float vc0[8] = {v00.x, v00.y, v00.z, v00.w, v01.x, v01.y, v01.z, v01.w};
    const float vc1[8] = {v10.x, v10.y, v10.z, v10.w, v11.x, v11.y, v11.z, v11.w};
    const float vc2[8] = {v20.x, v20.y, v20.z, v20.w, v21.x, v21.y, v21.z, v21.w};
    const float vc3[8] = {v30.x, v30.y, v30.z, v30.w, v31.x, v31.y, v31.z, v31.w};
#pragma unroll
    for (int hh = 0; hh < 8; ++hh) {
      const float wh = wa[hh];
      const float* sr = &su[hc * 8 + hh][ib];
      const float4 q0 = *reinterpret_cast<const float4*>(sr);      // same-addr broadcast
      const float4 q1 = *reinterpret_cast<const float4*>(sr + 4);  // same-addr broadcast
      const float uu[8] = {q0.x, q0.y, q0.z, q0.w, q1.x, q1.y, q1.z, q1.w};
      const float t0 = vc0[hh], t1 = vc1[hh], t2 = vc2[hh], t3 = vc3[hh];
#pragma unroll
      for (int m = 0; m < 8; ++m) {
        acc[m][0] = fmaf(wh, fabsf(uu[m] + t0), acc[m][0]);
        acc[m][1] = fmaf(wh, fabsf(uu[m] + t1), acc[m][1]);
        acc[m][2] = fmaf(wh, fabsf(uu[m] + t2), acc[m][2]);
        acc[m][3] = fmaf(wh, fabsf(uu[m] + t3), acc[m][3]);
      }
    }
  }

  const float bias2 = b2[0];
  const float bj0 = b[j0 + L];
  const float bj1 = b[j0 + 64 + L];
  const float bj2 = b[j0 + 128 + L];
  const float bj3 = b[j0 + 192 + L];

#pragma unroll
  for (int m = 0; m < 8; ++m) {
    const int i = i0 + ib + m;
    const float ai = a[i] + bias2;
    const float x0 = ai + bj0 + 0.5f * acc[m][0];
    const float x1 = ai + bj1 + 0.5f * acc[m][1];
    const float x2 = ai + bj2 + 0.5f * acc[m][2];
    const float x3 = ai + bj3 + 0.5f * acc[m][3];
    float r0 = 1.0f / (1.0f + __expf(-x0));
    float r1 = 1.0f / (1.0f + __expf(-x1));
    float r2 = 1.0f / (1.0f + __expf(-x2));
    float r3 = 1.0f / (1.0f + __expf(-x3));
    if (i == j0 + L) r0 = 0.0f;
    if (i == j0 + 64 + L) r1 = 0.0f;
    if (i == j0 + 128 + L) r2 = 0.0f;
    if (i == j0 + 192 + L) r3 = 0.0f;
    float* orow = out + (size_t)i * NN;
    orow[j0 + L] = r0;
    orow[j0 + 64 + L] = r1;
    orow[j0 + 128 + L] = r2;
    orow[j0 + 192 + L] = r3;
  }
}

extern "C" void kernel_launch(void* const* d_in, const int* in_sizes, int n_in,
                              void* d_out, int out_size, void* d_ws, size_t ws_size,
                              hipStream_t stream) {
  const float* z  = (const float*)d_in[0];
  const float* W1 = (const float*)d_in[1];
  const float* b1 = (const float*)d_in[2];
  const float* W2 = (const float*)d_in[3];
  const float* b2 = (const float*)d_in[4];
  float* out = (float*)d_out;

  float* u = (float*)d_ws;               // [2048][64]  512 KB
  float* v = u + (size_t)NN * HH;        // [2048][64]  512 KB
  float* a = v + (size_t)NN * HH;        // [2048]      8 KB
  float* b = a + NN;                     // [2048]      8 KB

  prep_kernel<<<NN / 8, 256, 0, stream>>>(z, W1, b1, W2, u, v, a, b);
  pair_kernel<<<dim3(NN / 256, NN / 32), 256, 0, stream>>>(u, v, a, b, W2, b2, out);
}

// Round 13
// 91.141 us; speedup vs baseline: 1.0484x; 1.0484x over previous
//
#include <hip/hip_runtime.h>
#include <math.h>

#define NN 2048
#define DD 64
#define HH 64

// ---------------------------------------------------------------------------
// Stage 1: u[i][h] = z[i]·Wa[h] + b1[h];  vt[h][j] = z[j]·Wb[h]  (transposed!)
// Plus fused rank-1 terms: a[i] = 0.5*sum_h W2[h]*u[i][h], b[j] likewise on v.
// ---------------------------------------------------------------------------
__global__ __launch_bounds__(256) void prep_kernel(
    const float* __restrict__ z, const float* __restrict__ W1,
    const float* __restrict__ b1, const float* __restrict__ W2,
    float* __restrict__ u, float* __restrict__ vt,
    float* __restrict__ a, float* __restrict__ b) {
  __shared__ float zs[8 * DD];
  const int t = threadIdx.x;
  const int i0 = blockIdx.x * 8;
  if (t < 128) {
    reinterpret_cast<float4*>(zs)[t] =
        reinterpret_cast<const float4*>(z + (size_t)i0 * DD)[t];
  }
  __syncthreads();

  const int hs = t & 127;
  const int rg = t >> 7;
  const int h = hs & 63;
  const int side = hs >> 6;
  const float* wrow = W1 + h * (2 * DD) + side * DD;

  float acc0 = 0.f, acc1 = 0.f, acc2 = 0.f, acc3 = 0.f;
#pragma unroll
  for (int d4 = 0; d4 < DD / 4; ++d4) {
    const float4 wv = reinterpret_cast<const float4*>(wrow)[d4];
    const float* z0 = zs + (rg * 4 + 0) * DD + d4 * 4;
    const float* z1 = z0 + DD;
    const float* z2 = z1 + DD;
    const float* z3 = z2 + DD;
    acc0 = fmaf(z0[3], wv.w, fmaf(z0[2], wv.z, fmaf(z0[1], wv.y, fmaf(z0[0], wv.x, acc0))));
    acc1 = fmaf(z1[3], wv.w, fmaf(z1[2], wv.z, fmaf(z1[1], wv.y, fmaf(z1[0], wv.x, acc1))));
    acc2 = fmaf(z2[3], wv.w, fmaf(z2[2], wv.z, fmaf(z2[1], wv.y, fmaf(z2[0], wv.x, acc2))));
    acc3 = fmaf(z3[3], wv.w, fmaf(z3[2], wv.z, fmaf(z3[1], wv.y, fmaf(z3[0], wv.x, acc3))));
  }
  const float bias = side ? 0.0f : b1[h];
  const float s0 = acc0 + bias, s1 = acc1 + bias, s2 = acc2 + bias, s3 = acc3 + bias;
  const int ib = i0 + rg * 4;
  if (side) {
    float* vrow = vt + (size_t)h * NN + ib;  // transposed layout [h][j]
    vrow[0] = s0; vrow[1] = s1; vrow[2] = s2; vrow[3] = s3;
  } else {
    u[(size_t)(ib + 0) * HH + h] = s0;
    u[(size_t)(ib + 1) * HH + h] = s1;
    u[(size_t)(ib + 2) * HH + h] = s2;
    u[(size_t)(ib + 3) * HH + h] = s3;
  }

  const float wh = W2[h];
  float r0 = wh * s0, r1 = wh * s1, r2 = wh * s2, r3 = wh * s3;
#pragma unroll
  for (int m = 1; m < 64; m <<= 1) {
    r0 += __shfl_xor(r0, m);
    r1 += __shfl_xor(r1, m);
    r2 += __shfl_xor(r2, m);
    r3 += __shfl_xor(r3, m);
  }
  if ((t & 63) == 0) {
    float* d2 = side ? b : a;
    d2[ib + 0] = 0.5f * r0;
    d2[ib + 1] = 0.5f * r1;
    d2[ib + 2] = 0.5f * r2;
    d2[ib + 3] = 0.5f * r3;
  }
}

// ---------------------------------------------------------------------------
// Stage 2: out[i][j] = sigmoid(a[i]+b[j]+b2 + 0.5*sum_h W2[h]*|u[i,h]+vt[h,j]|),
// diagonal zeroed.
// Design E: NO LDS, NO barriers. u[i_m][h] via v_readlane (lane L holds
// u[i_m][L]; literal lane index after full unroll -> SGPR broadcast).
// v via transposed vt: lane owns 4 CONSECUTIVE j -> all vt loads, b loads and
// out stores are perfectly coalesced b128 (1 KB/wave).
// Block: 4 waves, wave = 4 i x 256 j. Grid (8,128)=1024 blocks = 4 blocks/CU
// = 4 waves/SIMD occupancy. acc[4][4]+q[8]+ur[4] ~ 100 VGPR < 128 cap.
// ---------------------------------------------------------------------------
__global__ __launch_bounds__(256, 4) void pair_kernel(
    const float* __restrict__ u, const float* __restrict__ vt,
    const float* __restrict__ a, const float* __restrict__ b,
    const float* __restrict__ W2, const float* __restrict__ b2,
    float* __restrict__ out) {
  const int t = threadIdx.x;
  const int L = t & 63;               // lane
  const int w = t >> 6;               // wave 0..3
  const int i0 = blockIdx.y * 16 + w * 4;  // wave's 4 i-rows
  const int j0 = blockIdx.x * 256;         // block j-tile
  const int jL = j0 + 4 * L;               // lane's 4 consecutive j

  // lane L holds u[i0+m][L]; coalesced 256B loads
  float ur[4];
#pragma unroll
  for (int m = 0; m < 4; ++m) ur[m] = u[(size_t)(i0 + m) * HH + L];

  const float4* vt4 = reinterpret_cast<const float4*>(vt);  // [64][NN/4]
  const int vcol = (j0 >> 2) + L;

  float acc[4][4] = {};
#pragma unroll
  for (int hc = 0; hc < 8; ++hc) {    // 8 chunks of 8 h
    float4 q[8];
#pragma unroll
    for (int hh = 0; hh < 8; ++hh)    // coalesced b128: 4 consecutive j per lane
      q[hh] = vt4[(size_t)(hc * 8 + hh) * (NN / 4) + vcol];
#pragma unroll
    for (int hh = 0; hh < 8; ++hh) {
      const int h = hc * 8 + hh;
      const float wh = W2[h];         // literal-indexed uniform -> s_load
#pragma unroll
      for (int m = 0; m < 4; ++m) {
        const float um = __int_as_float(
            __builtin_amdgcn_readlane(__float_as_int(ur[m]), h));  // SGPR broadcast
        acc[m][0] = fmaf(wh, fabsf(um + q[hh].x), acc[m][0]);
        acc[m][1] = fmaf(wh, fabsf(um + q[hh].y), acc[m][1]);
        acc[m][2] = fmaf(wh, fabsf(um + q[hh].z), acc[m][2]);
        acc[m][3] = fmaf(wh, fabsf(um + q[hh].w), acc[m][3]);
      }
    }
  }

  const float bias2 = b2[0];
  const float4 bj = *reinterpret_cast<const float4*>(b + jL);
  const float bjv[4] = {bj.x, bj.y, bj.z, bj.w};

#pragma unroll
  for (int m = 0; m < 4; ++m) {
    const int i = i0 + m;
    const float ai = a[i] + bias2;
    float r[4];
#pragma unroll
    for (int c = 0; c < 4; ++c) {
      const float x = ai + bjv[c] + 0.5f * acc[m][c];
      r[c] = 1.0f / (1.0f + __expf(-x));
      if (i == jL + c) r[c] = 0.0f;
    }
    *reinterpret_cast<float4*>(out + (size_t)i * NN + jL) =
        make_float4(r[0], r[1], r[2], r[3]);
  }
}

extern "C" void kernel_launch(void* const* d_in, const int* in_sizes, int n_in,
                              void* d_out, int out_size, void* d_ws, size_t ws_size,
                              hipStream_t stream) {
  const float* z  = (const float*)d_in[0];
  const float* W1 = (const float*)d_in[1];
  const float* b1 = (const float*)d_in[2];
  const float* W2 = (const float*)d_in[3];
  const float* b2 = (const float*)d_in[4];
  float* out = (float*)d_out;

  float* u  = (float*)d_ws;               // [2048][64]  512 KB
  float* vt = u + (size_t)NN * HH;        // [64][2048]  512 KB (transposed)
  float* a  = vt + (size_t)NN * HH;       // [2048]      8 KB
  float* b  = a + NN;                     // [2048]      8 KB

  prep_kernel<<<NN / 8, 256, 0, stream>>>(z, W1, b1, W2, u, vt, a, b);
  pair_kernel<<<dim3(NN / 256, NN / 16), 256, 0, stream>>>(u, vt, a, b, W2, b2, out);
}